// Round 3
// baseline (247.673 us; speedup 1.0000x reference)
//
#include <hip/hip_runtime.h>
#include <cmath>

// Problem constants (match reference)
constexpr int Bc = 256;
constexpr int Lc = 512;
constexpr int Tc = 5;
constexpr int Dc = 300;   // 75 float4 per row; rows are 16B-aligned (1200 B)
constexpr int Cc = 3;

// ---------------------------------------------------------------------------
// Setup: v_aspect (initial vec) + mscore[b,l] = dot(emb[cx[b,l]], w_mem)*v_loc
// grid = B blocks, 512 threads (8 waves). Wave w handles l = w, w+8, ...
// ---------------------------------------------------------------------------
__global__ __launch_bounds__(512) void setup_kernel(
    const int* __restrict__ cx, const int* __restrict__ clen,
    const int* __restrict__ tx, const int* __restrict__ tlen,
    const int* __restrict__ tloc, const float* __restrict__ emb,
    const float* __restrict__ attn_w,
    float* __restrict__ mscore, float* __restrict__ vec)
{
  const int b = blockIdx.x;
  const int tid = threadIdx.x;
  const int cl = clen[b];
  const int loc = tloc[b];

  // v_aspect -> vec[b, :]
  if (tid < Dc) {
    const int tl = tlen[b];
    float s = 0.f;
#pragma unroll
    for (int t = 0; t < Tc; ++t) {
      if (t < tl) s += emb[tx[b * Tc + t] * Dc + tid];
    }
    vec[b * Dc + tid] = s / (float)tl;
  }

  const int wave = tid >> 6;
  const int lane = tid & 63;
  const float inv_cl = 1.0f / (float)cl;
  const float4* __restrict__ w4 = (const float4*)attn_w;  // w_mem as 75 float4

  for (int l = wave; l < Lc; l += 8) {
    float out = 0.f;
    if (l < cl) {
      const float4* er4 = (const float4*)(emb + (size_t)cx[b * Lc + l] * Dc);
      float4 e0 = er4[lane];
      float4 w0 = w4[lane];
      float p = e0.x * w0.x + e0.y * w0.y + e0.z * w0.z + e0.w * w0.w;
      if (lane < 11) {  // float4 indices 64..74
        float4 e1 = er4[64 + lane];
        float4 w1 = w4[64 + lane];
        p += e1.x * w1.x + e1.y * w1.y + e1.z * w1.z + e1.w * w1.w;
      }
#pragma unroll
      for (int off = 32; off; off >>= 1) p += __shfl_down(p, off, 64);
      const float vl = 1.0f - fabsf((float)(l - loc)) * inv_cl;
      out = p * vl;
    }
    if (lane == 0) mscore[b * Lc + l] = out;
  }
}

// ---------------------------------------------------------------------------
// One hop. grid = B blocks, 1024 threads (16 waves).
// ---------------------------------------------------------------------------
template <int LAST>
__global__ __launch_bounds__(1024) void hop_kernel(
    const int* __restrict__ cx, const int* __restrict__ clen,
    const int* __restrict__ tloc,
    const float* __restrict__ emb, const float* __restrict__ attn_w,
    const float* __restrict__ attn_b,
    const float* __restrict__ lin_w, const float* __restrict__ lin_b,
    const float* __restrict__ out_w, const float* __restrict__ out_b,
    const float* __restrict__ mscore, float* __restrict__ vec,
    float* __restrict__ out)
{
  __shared__ __align__(16) float vecS[Dc];
  __shared__ __align__(16) float loutP[3][Dc];   // 3-way k-split partials
  __shared__ __align__(16) float alphaS[Lc];     // alpha * v_loc
  __shared__ int   cxS[Lc];
  __shared__ float red[16];
  __shared__ float bcast[2];
  __shared__ __align__(16) float attnS[16][Dc];

  const int b = blockIdx.x;
  const int tid = threadIdx.x;
  const int wave = tid >> 6;
  const int lane = tid & 63;
  const int cl = clen[b];
  const int loc = tloc[b];
  const float inv_cl = 1.0f / (float)cl;

  if (tid < Dc) vecS[tid] = vec[b * Dc + tid];
  if (tid >= 512 && tid - 512 < Lc) cxS[tid - 512] = cx[b * Lc + (tid - 512)];
  __syncthreads();

  // sdot = dot(vec, w_vec) + attn_b  on wave 15 (tids 960..1023, unused below)
  if (wave == 15) {
    float p = 0.f;
    for (int i = lane; i < Dc; i += 64) p += vecS[i] * attn_w[Dc + i];
#pragma unroll
    for (int off = 32; off; off >>= 1) p += __shfl_down(p, off, 64);
    if (lane == 0) bcast[0] = p + attn_b[0];
  }
  // linear_out partials: 900 threads, thread (q,d) does k in [q*100, q*100+100)
  if (tid < 3 * Dc) {
    const int q = tid / Dc;
    const int d = tid - q * Dc;
    float lo = (q == 0) ? lin_b[d] : 0.f;
    const float* __restrict__ lw = lin_w + (q * 100) * Dc + d;
    const float* __restrict__ vk = vecS + q * 100;
#pragma unroll 4
    for (int k = 0; k < 100; ++k) lo += vk[k] * lw[k * Dc];
    loutP[q][d] = lo;
  }
  __syncthreads();
  const float sdot = bcast[0];

  // scores + softmax over L=512 (threads 0..511; waves 0..7)
  float s = -INFINITY;
  if (tid < Lc) {
    s = (tid < cl) ? tanhf(mscore[b * Lc + tid] + sdot) : -1e9f;
  }
  float m = s;
#pragma unroll
  for (int off = 32; off; off >>= 1) m = fmaxf(m, __shfl_down(m, off, 64));
  if (lane == 0) red[wave] = m;
  __syncthreads();
  if (tid == 0) {
    float mm = red[0];
    for (int w = 1; w < 8; ++w) mm = fmaxf(mm, red[w]);
    bcast[1] = mm;
  }
  __syncthreads();
  const float mx = bcast[1];

  float e = 0.f;
  if (tid < Lc) e = expf(s - mx);
  float sm = e;
#pragma unroll
  for (int off = 32; off; off >>= 1) sm += __shfl_down(sm, off, 64);
  if (lane == 0) red[wave] = sm;
  __syncthreads();
  if (tid == 0) {
    float ss = 0.f;
    for (int w = 0; w < 8; ++w) ss += red[w];
    bcast[0] = 1.0f / ss;
  }
  __syncthreads();
  if (tid < Lc) {
    // fold v_loc into the stored weight: gather loop becomes pure FMA
    const float vl = 1.0f - fabsf((float)(tid - loc)) * inv_cl;
    alphaS[tid] = e * bcast[0] * vl;
  }
  __syncthreads();

  // gather-accumulate: wave w handles l = w, w+16, ... (alpha==0 for l>=cl)
  // 2-way unrolled: two independent accumulator sets double outstanding VMEM.
  float4 a0 = {0.f, 0.f, 0.f, 0.f};
  float4 a1 = {0.f, 0.f, 0.f, 0.f};
  float4 b0 = {0.f, 0.f, 0.f, 0.f};
  float4 b1 = {0.f, 0.f, 0.f, 0.f};
  int l = wave;
  for (; l + 16 < cl; l += 32) {
    const float cA = alphaS[l];
    const float cB = alphaS[l + 16];
    const float4* rA = (const float4*)(emb + (size_t)cxS[l] * Dc);
    const float4* rB = (const float4*)(emb + (size_t)cxS[l + 16] * Dc);
    float4 vA0 = rA[lane];
    float4 vB0 = rB[lane];
    a0.x += cA * vA0.x; a0.y += cA * vA0.y; a0.z += cA * vA0.z; a0.w += cA * vA0.w;
    b0.x += cB * vB0.x; b0.y += cB * vB0.y; b0.z += cB * vB0.z; b0.w += cB * vB0.w;
    if (lane < 11) {
      float4 vA1 = rA[64 + lane];
      float4 vB1 = rB[64 + lane];
      a1.x += cA * vA1.x; a1.y += cA * vA1.y; a1.z += cA * vA1.z; a1.w += cA * vA1.w;
      b1.x += cB * vB1.x; b1.y += cB * vB1.y; b1.z += cB * vB1.z; b1.w += cB * vB1.w;
    }
  }
  for (; l < cl; l += 16) {
    const float cA = alphaS[l];
    const float4* rA = (const float4*)(emb + (size_t)cxS[l] * Dc);
    float4 vA0 = rA[lane];
    a0.x += cA * vA0.x; a0.y += cA * vA0.y; a0.z += cA * vA0.z; a0.w += cA * vA0.w;
    if (lane < 11) {
      float4 vA1 = rA[64 + lane];
      a1.x += cA * vA1.x; a1.y += cA * vA1.y; a1.z += cA * vA1.z; a1.w += cA * vA1.w;
    }
  }
  a0.x += b0.x; a0.y += b0.y; a0.z += b0.z; a0.w += b0.w;
  a1.x += b1.x; a1.y += b1.y; a1.z += b1.z; a1.w += b1.w;
  {
    float4* row = (float4*)attnS[wave];
    row[lane] = a0;
    if (lane < 11) row[64 + lane] = a1;
  }
  __syncthreads();

  if (tid < Dc) {
    float v = loutP[0][tid] + loutP[1][tid] + loutP[2][tid];
#pragma unroll
    for (int w = 0; w < 16; ++w) v += attnS[w][tid];
    if (!LAST) {
      vec[b * Dc + tid] = v;   // only block b touches row b: in-place safe
    } else {
      vecS[tid] = v;
    }
  }
  if (LAST) {
    __syncthreads();
    if (tid < Cc) {
      float o = out_b[tid];
      for (int d = 0; d < Dc; ++d) o += vecS[d] * out_w[d * Cc + tid];
      out[b * Cc + tid] = o;
    }
  }
}

extern "C" void kernel_launch(void* const* d_in, const int* in_sizes, int n_in,
                              void* d_out, int out_size, void* d_ws, size_t ws_size,
                              hipStream_t stream) {
  const int*   cx     = (const int*)  d_in[0];
  const int*   clen   = (const int*)  d_in[1];
  const int*   tx     = (const int*)  d_in[2];
  const int*   tlen   = (const int*)  d_in[3];
  const int*   tloc   = (const int*)  d_in[4];
  const float* emb    = (const float*)d_in[5];
  const float* attn_w = (const float*)d_in[6];
  const float* attn_b = (const float*)d_in[7];
  const float* lin_w  = (const float*)d_in[8];
  const float* lin_b  = (const float*)d_in[9];
  const float* out_w  = (const float*)d_in[10];
  const float* out_b  = (const float*)d_in[11];
  float* out = (float*)d_out;

  // workspace: mscore (B*L f32) | vec (B*D f32)   -> ~0.83 MB
  float* mscore = (float*)d_ws;
  float* vecbuf = mscore + Bc * Lc;

  setup_kernel<<<Bc, 512, 0, stream>>>(cx, clen, tx, tlen, tloc, emb, attn_w,
                                       mscore, vecbuf);
  hop_kernel<0><<<Bc, 1024, 0, stream>>>(cx, clen, tloc, emb, attn_w, attn_b,
                                         lin_w, lin_b, out_w, out_b,
                                         mscore, vecbuf, out);
  hop_kernel<0><<<Bc, 1024, 0, stream>>>(cx, clen, tloc, emb, attn_w, attn_b,
                                         lin_w, lin_b, out_w, out_b,
                                         mscore, vecbuf, out);
  hop_kernel<1><<<Bc, 1024, 0, stream>>>(cx, clen, tloc, emb, attn_w, attn_b,
                                         lin_w, lin_b, out_w, out_b,
                                         mscore, vecbuf, out);
}

// Round 4
// 212.680 us; speedup vs baseline: 1.1645x; 1.1645x over previous
//
#include <hip/hip_runtime.h>
#include <cmath>

// Problem constants (match reference)
constexpr int Bc = 256;
constexpr int Lc = 512;
constexpr int Tc = 5;
constexpr int Dc = 300;   // 75 float4 per row; rows are 16B-aligned (1200 B)
constexpr int Cc = 3;
constexpr int Vc = 50000;
constexpr int NCH = 8;            // L-chunks per batch row for the gather
constexpr int CHL = Lc / NCH;     // 64 l per chunk
constexpr int DP  = 304;          // padded partial row (floats, 16B-aligned)

// ---------------------------------------------------------------------------
// K0: escore[v] = dot(emb[v], w_mem) for ALL vocab rows — one coalesced
// 60 MB stream (also warms L3 with emb for the gather kernels).
// Blocks >= Vc/4 compute v_aspect -> vec0.
// ---------------------------------------------------------------------------
__global__ __launch_bounds__(256) void escore_kernel(
    const float* __restrict__ emb, const float* __restrict__ attn_w,
    const int* __restrict__ tx, const int* __restrict__ tlen,
    float* __restrict__ escore, float* __restrict__ vec0)
{
  const int tid = threadIdx.x;
  if (blockIdx.x < Vc / 4) {
    const int lane = tid & 63;
    const int v = blockIdx.x * 4 + (tid >> 6);
    const float4* er4 = (const float4*)(emb + (size_t)v * Dc);
    const float4* w4  = (const float4*)attn_w;
    float4 e0 = er4[lane], w0 = w4[lane];
    float p = e0.x*w0.x + e0.y*w0.y + e0.z*w0.z + e0.w*w0.w;
    if (lane < 11) {
      float4 e1 = er4[64+lane], w1 = w4[64+lane];
      p += e1.x*w1.x + e1.y*w1.y + e1.z*w1.z + e1.w*w1.w;
    }
#pragma unroll
    for (int off = 32; off; off >>= 1) p += __shfl_down(p, off, 64);
    if (lane == 0) escore[v] = p;
  } else {
    const int b = blockIdx.x - Vc / 4;
    const int tl = tlen[b];
    for (int d = tid; d < Dc; d += 256) {
      float s = 0.f;
#pragma unroll
      for (int t = 0; t < Tc; ++t)
        if (t < tl) s += emb[(size_t)tx[b*Tc + t] * Dc + d];
      vec0[b*Dc + d] = s / (float)tl;
    }
  }
}

// ---------------------------------------------------------------------------
// Score kernel (per hop): build vec (v_aspect on hop 1, else lout + partials),
// sdot, linear_out, scores = tanh(escore[cx]*v_loc + sdot), softmax,
// write alphaw (= alpha*v_loc) and the new lout.  grid = B, 1024 threads.
// ---------------------------------------------------------------------------
template <int FIRST>
__global__ __launch_bounds__(1024) void score_kernel(
    const int* __restrict__ cx, const int* __restrict__ clen,
    const int* __restrict__ tloc,
    const float* __restrict__ escore, const float* __restrict__ attn_w,
    const float* __restrict__ attn_b,
    const float* __restrict__ lin_w, const float* __restrict__ lin_b,
    const float* __restrict__ vec0, const float* __restrict__ part,
    float* __restrict__ lout, float* __restrict__ alphaw)
{
  __shared__ __align__(16) float vecS[Dc];
  __shared__ __align__(16) float loutP[3][Dc];
  __shared__ float red[16];
  __shared__ float bcast[2];

  const int b = blockIdx.x;
  const int tid = threadIdx.x;
  const int wave = tid >> 6;
  const int lane = tid & 63;
  const int cl = clen[b];
  const int loc = tloc[b];
  const float inv_cl = 1.0f / (float)cl;

  if (tid < Dc) {
    if (FIRST) {
      vecS[tid] = vec0[b*Dc + tid];
    } else {
      float v = lout[b*Dc + tid];
#pragma unroll
      for (int c = 0; c < NCH; ++c) v += part[((size_t)b*NCH + c)*DP + tid];
      vecS[tid] = v;
    }
  }
  __syncthreads();

  // sdot on wave 15 (tids 960..1023, unused by linear_out)
  if (wave == 15) {
    float p = 0.f;
    for (int i = lane; i < Dc; i += 64) p += vecS[i] * attn_w[Dc + i];
#pragma unroll
    for (int off = 32; off; off >>= 1) p += __shfl_down(p, off, 64);
    if (lane == 0) bcast[0] = p + attn_b[0];
  }
  // linear_out partials: threads 0..899, thread (q,d) does k in [q*100,q*100+100)
  if (tid < 3 * Dc) {
    const int q = tid / Dc;
    const int d = tid - q * Dc;
    float lo = (q == 0) ? lin_b[d] : 0.f;
    const float* __restrict__ lw = lin_w + (q * 100) * Dc + d;
    const float* __restrict__ vk = vecS + q * 100;
#pragma unroll 4
    for (int k = 0; k < 100; ++k) lo += vk[k] * lw[k * Dc];
    loutP[q][d] = lo;
  }
  __syncthreads();
  const float sdot = bcast[0];

  // new lout for next hop (in-place safe: only block b touches row b,
  // and the !FIRST read of lout happened before the first barrier)
  if (tid < Dc) lout[b*Dc + tid] = loutP[0][tid] + loutP[1][tid] + loutP[2][tid];

  // scores + softmax over L=512 (threads 0..511; waves 0..7)
  float s = -INFINITY, vl = 0.f;
  if (tid < Lc) {
    vl = 1.0f - fabsf((float)(tid - loc)) * inv_cl;
    s = (tid < cl) ? tanhf(escore[cx[b*Lc + tid]] * vl + sdot) : -1e9f;
  }
  float m = s;
#pragma unroll
  for (int off = 32; off; off >>= 1) m = fmaxf(m, __shfl_down(m, off, 64));
  if (lane == 0) red[wave] = m;
  __syncthreads();
  if (tid == 0) {
    float mm = red[0];
    for (int w = 1; w < 8; ++w) mm = fmaxf(mm, red[w]);
    bcast[1] = mm;
  }
  __syncthreads();
  const float mx = bcast[1];

  float e = 0.f;
  if (tid < Lc) e = expf(s - mx);
  float sm = e;
#pragma unroll
  for (int off = 32; off; off >>= 1) sm += __shfl_down(sm, off, 64);
  if (lane == 0) red[wave] = sm;
  __syncthreads();
  if (tid == 0) {
    float ss = 0.f;
    for (int w = 0; w < 8; ++w) ss += red[w];
    bcast[0] = 1.0f / ss;
  }
  __syncthreads();
  if (tid < Lc) alphaw[b*Lc + tid] = e * bcast[0] * vl;  // fold v_loc in
}

// ---------------------------------------------------------------------------
// Gather kernel: block (b,c) accumulates sum_{l in chunk c, l<cl}
// alphaw[l] * emb[cx[b,l]] into part[b][c][:].  grid = B*NCH, 256 threads.
// ---------------------------------------------------------------------------
__global__ __launch_bounds__(256) void gather_kernel(
    const int* __restrict__ cx, const int* __restrict__ clen,
    const float* __restrict__ emb, const float* __restrict__ alphaw,
    float* __restrict__ part)
{
  const int bc = blockIdx.x;
  const int b = bc >> 3, c = bc & 7;
  const int tid = threadIdx.x, wave = tid >> 6, lane = tid & 63;
  const int l0 = c * CHL;
  const int lmax = min(CHL, clen[b] - l0);
  float* __restrict__ pr = part + (size_t)bc * DP;
  if (lmax <= 0) {  // whole chunk masked: zero the partial (ws is poisoned)
    for (int d = tid; d < Dc; d += 256) pr[d] = 0.f;
    return;
  }
  __shared__ float aS[CHL];
  __shared__ int cS[CHL];
  __shared__ __align__(16) float attnP[4][DP];
  if (tid < CHL) {
    aS[tid] = alphaw[b*Lc + l0 + tid];
    cS[tid] = cx[b*Lc + l0 + tid];
  }
  __syncthreads();

  // wave w handles local l = w, w+4, ... ; 2-way unroll for VMEM ILP
  float4 a0{0,0,0,0}, a1{0,0,0,0}, b0{0,0,0,0}, b1{0,0,0,0};
  int l = wave;
  for (; l + 4 < lmax; l += 8) {
    const float cA = aS[l], cB = aS[l+4];
    const float4* rA = (const float4*)(emb + (size_t)cS[l]   * Dc);
    const float4* rB = (const float4*)(emb + (size_t)cS[l+4] * Dc);
    float4 vA = rA[lane], vB = rB[lane];
    a0.x += cA*vA.x; a0.y += cA*vA.y; a0.z += cA*vA.z; a0.w += cA*vA.w;
    b0.x += cB*vB.x; b0.y += cB*vB.y; b0.z += cB*vB.z; b0.w += cB*vB.w;
    if (lane < 11) {
      float4 uA = rA[64+lane], uB = rB[64+lane];
      a1.x += cA*uA.x; a1.y += cA*uA.y; a1.z += cA*uA.z; a1.w += cA*uA.w;
      b1.x += cB*uB.x; b1.y += cB*uB.y; b1.z += cB*uB.z; b1.w += cB*uB.w;
    }
  }
  for (; l < lmax; l += 4) {
    const float cA = aS[l];
    const float4* rA = (const float4*)(emb + (size_t)cS[l] * Dc);
    float4 vA = rA[lane];
    a0.x += cA*vA.x; a0.y += cA*vA.y; a0.z += cA*vA.z; a0.w += cA*vA.w;
    if (lane < 11) {
      float4 uA = rA[64+lane];
      a1.x += cA*uA.x; a1.y += cA*uA.y; a1.z += cA*uA.z; a1.w += cA*uA.w;
    }
  }
  a0.x += b0.x; a0.y += b0.y; a0.z += b0.z; a0.w += b0.w;
  a1.x += b1.x; a1.y += b1.y; a1.z += b1.z; a1.w += b1.w;
  {
    float4* row = (float4*)attnP[wave];
    row[lane] = a0;
    if (lane < 11) row[64 + lane] = a1;
  }
  __syncthreads();
  for (int d = tid; d < Dc; d += 256)
    pr[d] = attnP[0][d] + attnP[1][d] + attnP[2][d] + attnP[3][d];
}

// ---------------------------------------------------------------------------
// Final: vec = lout + sum partials; logits = vec @ out_w + out_b.
// grid = B, 256 threads (waves 0..2 compute the 3 logits).
// ---------------------------------------------------------------------------
__global__ __launch_bounds__(256) void final_kernel(
    const float* __restrict__ lout, const float* __restrict__ part,
    const float* __restrict__ out_w, const float* __restrict__ out_b,
    float* __restrict__ out)
{
  __shared__ float vecS[Dc];
  const int b = blockIdx.x, tid = threadIdx.x;
  for (int d = tid; d < Dc; d += 256) {
    float v = lout[b*Dc + d];
#pragma unroll
    for (int c = 0; c < NCH; ++c) v += part[((size_t)b*NCH + c)*DP + d];
    vecS[d] = v;
  }
  __syncthreads();
  const int wave = tid >> 6, lane = tid & 63;
  if (wave < Cc) {
    float p = 0.f;
    for (int i = lane; i < Dc; i += 64) p += vecS[i] * out_w[i*Cc + wave];
#pragma unroll
    for (int off = 32; off; off >>= 1) p += __shfl_down(p, off, 64);
    if (lane == 0) out[b*Cc + wave] = p + out_b[wave];
  }
}

extern "C" void kernel_launch(void* const* d_in, const int* in_sizes, int n_in,
                              void* d_out, int out_size, void* d_ws, size_t ws_size,
                              hipStream_t stream) {
  const int*   cx     = (const int*)  d_in[0];
  const int*   clen   = (const int*)  d_in[1];
  const int*   tx     = (const int*)  d_in[2];
  const int*   tlen   = (const int*)  d_in[3];
  const int*   tloc   = (const int*)  d_in[4];
  const float* emb    = (const float*)d_in[5];
  const float* attn_w = (const float*)d_in[6];
  const float* attn_b = (const float*)d_in[7];
  const float* lin_w  = (const float*)d_in[8];
  const float* lin_b  = (const float*)d_in[9];
  const float* out_w  = (const float*)d_in[10];
  const float* out_b  = (const float*)d_in[11];
  float* out = (float*)d_out;

  // ws layout (floats): escore | vec0 | lout | alphaw | part   (~3.8 MB)
  float* escore = (float*)d_ws;
  float* vec0   = escore + Vc;
  float* lout   = vec0   + Bc * Dc;
  float* alphaw = lout   + Bc * Dc;
  float* part   = alphaw + Bc * Lc;

  escore_kernel<<<Vc/4 + Bc, 256, 0, stream>>>(emb, attn_w, tx, tlen,
                                               escore, vec0);
  // hop 1
  score_kernel<1><<<Bc, 1024, 0, stream>>>(cx, clen, tloc, escore, attn_w,
                                           attn_b, lin_w, lin_b, vec0, part,
                                           lout, alphaw);
  gather_kernel<<<Bc*NCH, 256, 0, stream>>>(cx, clen, emb, alphaw, part);
  // hop 2
  score_kernel<0><<<Bc, 1024, 0, stream>>>(cx, clen, tloc, escore, attn_w,
                                           attn_b, lin_w, lin_b, vec0, part,
                                           lout, alphaw);
  gather_kernel<<<Bc*NCH, 256, 0, stream>>>(cx, clen, emb, alphaw, part);
  // hop 3
  score_kernel<0><<<Bc, 1024, 0, stream>>>(cx, clen, tloc, escore, attn_w,
                                           attn_b, lin_w, lin_b, vec0, part,
                                           lout, alphaw);
  gather_kernel<<<Bc*NCH, 256, 0, stream>>>(cx, clen, emb, alphaw, part);
  // vec -> logits
  final_kernel<<<Bc, 256, 0, stream>>>(lout, part, out_w, out_b, out);
}

// Round 7
// 184.093 us; speedup vs baseline: 1.3454x; 1.1553x over previous
//
#include <hip/hip_runtime.h>
#include <cmath>

// Problem constants (match reference)
constexpr int Bc = 256;
constexpr int Lc = 512;
constexpr int Tc = 5;
constexpr int Dc = 300;    // 75 float4 per row; rows are 16B-aligned (1200 B)
constexpr int Cc = 3;
constexpr int Vc = 50000;
constexpr int TGT_P = 304; // padded target-vector pitch (floats, 16B-aligned)

// Target-vector table layout (12 rows of TGT_P floats in ws):
//  0: w_mem            1: w_vec          2: p2 = lin_w @ w_vec
//  3-5: Q0 cols (out_w) 6-8: Q1 = lin_w@Q0 cols   9-11: Q2 = lin_w@Q1 cols
// etab[v][12] = emb[v] . tgt[j]  (packed, 48 B/row)

__device__ __forceinline__ float wave_dot300(const float* __restrict__ x,
                                             const float* __restrict__ y,
                                             int lane) {
  const float4* x4 = (const float4*)x;
  const float4* y4 = (const float4*)y;
  float4 a = x4[lane], b = y4[lane];
  float p = a.x*b.x + a.y*b.y + a.z*b.z + a.w*b.w;
  if (lane < 11) {
    float4 c = x4[64 + lane], d = y4[64 + lane];
    p += c.x*d.x + c.y*d.y + c.z*d.z + c.w*d.w;
  }
#pragma unroll
  for (int off = 32; off; off >>= 1) p += __shfl_down(p, off, 64);
  return p;  // valid on lane 0
}

// ---------------------------------------------------------------------------
// prep1: p2 (blocks 0-74), Q1 (75-299), copies (300), vec0 (301-556)
// ---------------------------------------------------------------------------
__global__ __launch_bounds__(256) void prep1_kernel(
    const float* __restrict__ lin_w, const float* __restrict__ attn_w,
    const float* __restrict__ out_w, const int* __restrict__ tx,
    const int* __restrict__ tlen, const float* __restrict__ emb,
    float* __restrict__ tgt, float* __restrict__ vec0)
{
  const int blk = blockIdx.x, tid = threadIdx.x;
  const int wave = tid >> 6, lane = tid & 63;
  if (blk < 75) {                       // p2[k] = lin_w row k . w_vec
    const int k = blk * 4 + wave;
    float p = wave_dot300(lin_w + (size_t)k * Dc, attn_w + Dc, lane);
    if (lane == 0) tgt[2 * TGT_P + k] = p;
  } else if (blk < 300) {               // Q1[k][c] = lin_w row k . out_w col c
    const int idx = (blk - 75) * 4 + wave;   // 0..899
    const int k = idx / 3, c = idx - 3 * (idx / 3);
    const float4* x4 = (const float4*)(lin_w + (size_t)k * Dc);
    float4 a = x4[lane];
    const int d0 = 4 * lane;
    float p = a.x*out_w[(d0+0)*Cc+c] + a.y*out_w[(d0+1)*Cc+c]
            + a.z*out_w[(d0+2)*Cc+c] + a.w*out_w[(d0+3)*Cc+c];
    if (lane < 11) {
      float4 bb = x4[64 + lane];
      const int d1 = 256 + 4 * lane;
      p += bb.x*out_w[(d1+0)*Cc+c] + bb.y*out_w[(d1+1)*Cc+c]
         + bb.z*out_w[(d1+2)*Cc+c] + bb.w*out_w[(d1+3)*Cc+c];
    }
#pragma unroll
    for (int off = 32; off; off >>= 1) p += __shfl_down(p, off, 64);
    if (lane == 0) tgt[(6 + c) * TGT_P + k] = p;
  } else if (blk == 300) {              // copies + out_w transpose
    for (int i = tid; i < Dc; i += 256) {
      tgt[0 * TGT_P + i] = attn_w[i];
      tgt[1 * TGT_P + i] = attn_w[Dc + i];
      tgt[3 * TGT_P + i] = out_w[i * Cc + 0];
      tgt[4 * TGT_P + i] = out_w[i * Cc + 1];
      tgt[5 * TGT_P + i] = out_w[i * Cc + 2];
    }
  } else {                              // vec0 = v_aspect, b = blk-301
    const int b = blk - 301;
    const int tl = tlen[b];
    for (int d = tid; d < Dc; d += 256) {
      float s = 0.f;
#pragma unroll
      for (int t = 0; t < Tc; ++t)
        if (t < tl) s += emb[(size_t)tx[b * Tc + t] * Dc + d];
      vec0[b * Dc + d] = s / (float)tl;
    }
  }
}

// ---------------------------------------------------------------------------
// prep2: Q2[k][c] = lin_w row k . Q1 col c   (grid 225 x 256)
// ---------------------------------------------------------------------------
__global__ __launch_bounds__(256) void prep2_kernel(
    const float* __restrict__ lin_w, float* __restrict__ tgt)
{
  const int idx = blockIdx.x * 4 + (threadIdx.x >> 6);  // 0..899
  const int lane = threadIdx.x & 63;
  const int k = idx / 3, c = idx - 3 * (idx / 3);
  float p = wave_dot300(lin_w + (size_t)k * Dc, tgt + (6 + c) * TGT_P, lane);
  if (lane == 0) tgt[(9 + c) * TGT_P + k] = p;
}

// ---------------------------------------------------------------------------
// etab: one coalesced pass over emb; 12 dots per vocab row.
// grid 1024 x 256 (4096 waves, wave-per-row).
// ---------------------------------------------------------------------------
__global__ __launch_bounds__(256, 3) void etab_kernel(
    const float* __restrict__ emb, const float* __restrict__ tgt,
    float* __restrict__ etab)
{
  const int wid = blockIdx.x * 4 + (threadIdx.x >> 6);
  const int lane = threadIdx.x & 63;
  const float4* tgt4 = (const float4*)tgt;   // TGT_P/4 = 76 float4 per row
  float4 wlo[12], whi[12];
#pragma unroll
  for (int j = 0; j < 12; ++j) {
    wlo[j] = tgt4[j * 76 + lane];
    whi[j] = (lane < 11) ? tgt4[j * 76 + 64 + lane] : float4{0.f,0.f,0.f,0.f};
  }
  for (int v = wid; v < Vc; v += 4096) {
    const float4* r4 = (const float4*)(emb + (size_t)v * Dc);
    float4 lo = r4[lane];
    float4 hi = (lane < 11) ? r4[64 + lane] : float4{0.f,0.f,0.f,0.f};
    float acc[12];
#pragma unroll
    for (int j = 0; j < 12; ++j) {
      float a = lo.x*wlo[j].x + lo.y*wlo[j].y + lo.z*wlo[j].z + lo.w*wlo[j].w
              + hi.x*whi[j].x + hi.y*whi[j].y + hi.z*whi[j].z + hi.w*whi[j].w;
#pragma unroll
      for (int off = 32; off; off >>= 1) a += __shfl_down(a, off, 64);
      acc[j] = a;
    }
    if (lane == 0) {
      float4* ot = (float4*)(etab + (size_t)v * 12);
      ot[0] = float4{acc[0], acc[1], acc[2],  acc[3]};
      ot[1] = float4{acc[4], acc[5], acc[6],  acc[7]};
      ot[2] = float4{acc[8], acc[9], acc[10], acc[11]};
    }
  }
}

// ---------------------------------------------------------------------------
// hops: per-b scalar 3-hop chain. grid 256 x 512 (thread = l).
// ---------------------------------------------------------------------------
template <int N>
__device__ __forceinline__ void breduceN(float (&v)[N], float (*sred)[8],
                                         float* outRB, int wave, int lane,
                                         int tid) {
#pragma unroll
  for (int j = 0; j < N; ++j) {
    float a = v[j];
#pragma unroll
    for (int off = 32; off; off >>= 1) a += __shfl_down(a, off, 64);
    if (lane == 0) sred[wave][j] = a;
  }
  __syncthreads();
  if (tid == 0) {
#pragma unroll
    for (int j = 0; j < N; ++j) {
      float s = 0.f;
      for (int w = 0; w < 8; ++w) s += sred[w][j];
      outRB[j] = s;
    }
  }
  __syncthreads();
}

__device__ __forceinline__ float lds_dot300(const float* x,
                                            const float* __restrict__ y,
                                            int lane) {
  float p = 0.f;
  for (int i = lane; i < Dc; i += 64) p += x[i] * y[i];
#pragma unroll
  for (int off = 32; off; off >>= 1) p += __shfl_down(p, off, 64);
  return p;
}

__global__ __launch_bounds__(512) void hops_kernel(
    const int* __restrict__ cx, const int* __restrict__ clen,
    const int* __restrict__ tloc,
    const float* __restrict__ etab, const float* __restrict__ tgt,
    const float* __restrict__ vec0, const float* __restrict__ lin_w,
    const float* __restrict__ lin_b, const float* __restrict__ attn_b,
    const float* __restrict__ out_b, float* __restrict__ out)
{
  __shared__ float vec0S[Dc];
  __shared__ float lv0S[Dc];
  __shared__ float sred[8][8];
  __shared__ float CB[12];   // 0:a1 1:a2 2:cb1 3:cb2 4-6:cbl+ob 7:a3 8-10:qv
  __shared__ float RB[12];   // 0:A0f1 1:A0f2 2-4:A0g2 5:A1f1 6-8:A1g1 9-11:A2g0
  __shared__ float XB[2];

  const int b = blockIdx.x, tid = threadIdx.x;
  const int wave = tid >> 6, lane = tid & 63;
  const int cl = clen[b], loc = tloc[b];
  const float inv_cl = 1.0f / (float)cl;

  if (tid < Dc) vec0S[tid] = vec0[b * Dc + tid];

  // per-l scalars from etab (held in registers across all 3 hops)
  const int cxv = cx[b * Lc + tid];
  const float4* et = (const float4*)(etab + (size_t)cxv * 12);
  const float4 t0 = et[0], t1 = et[1], t2 = et[2];
  const float vl = 1.0f - fabsf((float)(tid - loc)) * inv_cl;
  const float m_l  = t0.x * vl, f1 = t0.y * vl, f2 = t0.z * vl;
  const float g0c0 = t0.w * vl, g0c1 = t1.x * vl, g0c2 = t1.y * vl;
  const float g1c0 = t1.z * vl, g1c1 = t1.w * vl, g1c2 = t2.x * vl;
  const float g2c0 = t2.y * vl, g2c1 = t2.z * vl, g2c2 = t2.w * vl;
  __syncthreads();

  // lv0 = vec0 @ lin_w (threads 0..299); const dots on waves 5-7
  if (tid < Dc) {
    float lv = 0.f;
    const float* __restrict__ lw = lin_w + tid;
#pragma unroll 4
    for (int k = 0; k < Dc; ++k) lv += vec0S[k] * lw[k * Dc];
    lv0S[tid] = lv;
  } else if (wave == 5) {
    float p = lds_dot300(vec0S, tgt + 1 * TGT_P, lane);   // a1
    if (lane == 0) CB[0] = p;
    p = lds_dot300(vec0S, tgt + 2 * TGT_P, lane);         // a2
    if (lane == 0) CB[1] = p;
  } else if (wave == 6) {
    float p = lds_dot300(lin_b, tgt + 1 * TGT_P, lane);   // cb1
    if (lane == 0) CB[2] = p;
    p = lds_dot300(lin_b, tgt + 2 * TGT_P, lane);         // cb2
    if (lane == 0) CB[3] = p;
  } else if (wave == 7) {
#pragma unroll
    for (int c = 0; c < 3; ++c) {
      float p = 0.f;
      for (int i = lane; i < Dc; i += 64)
        p += lin_b[i] * (tgt[(3+c)*TGT_P + i] + tgt[(6+c)*TGT_P + i] +
                         tgt[(9+c)*TGT_P + i]);
#pragma unroll
      for (int off = 32; off; off >>= 1) p += __shfl_down(p, off, 64);
      if (lane == 0) CB[4 + c] = p + out_b[c];            // cbl_c + ob_c
    }
  }
  __syncthreads();
  if (wave == 5) {
    float p = lds_dot300(lv0S, tgt + 2 * TGT_P, lane);    // a3 = lv0.p2
    if (lane == 0) CB[7] = p;
    p = lds_dot300(lv0S, tgt + 11 * TGT_P, lane);         // qv2
    if (lane == 0) CB[10] = p;
  } else if (wave == 6) {
    float p = lds_dot300(lv0S, tgt + 9 * TGT_P, lane);    // qv0
    if (lane == 0) CB[8] = p;
  } else if (wave == 7) {
    float p = lds_dot300(lv0S, tgt + 10 * TGT_P, lane);   // qv1
    if (lane == 0) CB[9] = p;
  }
  __syncthreads();

  const float ab = attn_b[0];
  float sdot = CB[0] + ab;

#pragma unroll
  for (int h = 0; h < 3; ++h) {
    float s = (tid < cl) ? tanhf(m_l + sdot) : -1e9f;
    float mx = s;
#pragma unroll
    for (int off = 32; off; off >>= 1) mx = fmaxf(mx, __shfl_down(mx, off, 64));
    if (lane == 0) sred[wave][0] = mx;
    __syncthreads();
    if (tid == 0) {
      float mm = sred[0][0];
      for (int w = 1; w < 8; ++w) mm = fmaxf(mm, sred[w][0]);
      XB[0] = mm;
    }
    __syncthreads();
    float e = expf(s - XB[0]);                 // masked rows -> exactly 0
    float sm = e;
#pragma unroll
    for (int off = 32; off; off >>= 1) sm += __shfl_down(sm, off, 64);
    if (lane == 0) sred[wave][0] = sm;
    __syncthreads();
    if (tid == 0) {
      float ss = 0.f;
      for (int w = 0; w < 8; ++w) ss += sred[w][0];
      XB[1] = 1.0f / ss;
    }
    __syncthreads();
    const float alpha = e * XB[1];

    if (h == 0) {
      float v[5] = {alpha*f1, alpha*f2, alpha*g2c0, alpha*g2c1, alpha*g2c2};
      breduceN<5>(v, sred, RB + 0, wave, lane, tid);
      sdot = RB[0] + CB[1] + CB[2] + ab;
    } else if (h == 1) {
      float v[4] = {alpha*f1, alpha*g1c0, alpha*g1c1, alpha*g1c2};
      breduceN<4>(v, sred, RB + 5, wave, lane, tid);
      sdot = RB[5] + RB[1] + CB[7] + CB[3] + CB[2] + ab;
    } else {
      float v[3] = {alpha*g0c0, alpha*g0c1, alpha*g0c2};
      breduceN<3>(v, sred, RB + 9, wave, lane, tid);
    }
  }

  if (tid < Cc)
    out[b * Cc + tid] = RB[9 + tid] + RB[6 + tid] + RB[2 + tid] +
                        CB[8 + tid] + CB[4 + tid];
}

extern "C" void kernel_launch(void* const* d_in, const int* in_sizes, int n_in,
                              void* d_out, int out_size, void* d_ws, size_t ws_size,
                              hipStream_t stream) {
  const int*   cx     = (const int*)  d_in[0];
  const int*   clen   = (const int*)  d_in[1];
  const int*   tx     = (const int*)  d_in[2];
  const int*   tlen   = (const int*)  d_in[3];
  const int*   tloc   = (const int*)  d_in[4];
  const float* emb    = (const float*)d_in[5];
  const float* attn_w = (const float*)d_in[6];
  const float* attn_b = (const float*)d_in[7];
  const float* lin_w  = (const float*)d_in[8];
  const float* lin_b  = (const float*)d_in[9];
  const float* out_w  = (const float*)d_in[10];
  const float* out_b  = (const float*)d_in[11];
  float* out = (float*)d_out;

  // ws layout (floats): tgt[12][304] | vec0[256*300] | etab[50000*12]  ~2.7 MB
  float* tgt   = (float*)d_ws;
  float* vec0  = tgt  + 12 * TGT_P;
  float* etab  = vec0 + Bc * Dc;

  prep1_kernel<<<557, 256, 0, stream>>>(lin_w, attn_w, out_w, tx, tlen, emb,
                                        tgt, vec0);
  prep2_kernel<<<225, 256, 0, stream>>>(lin_w, tgt);
  etab_kernel<<<1024, 256, 0, stream>>>(emb, tgt, etab);
  hops_kernel<<<Bc, 512, 0, stream>>>(cx, clen, tloc, etab, tgt, vec0,
                                      lin_w, lin_b, attn_b, out_b, out);
}